// Round 1
// baseline (1159.692 us; speedup 1.0000x reference)
//
#include <hip/hip_runtime.h>
#include <math.h>

// FNO: N=16, H=64, NT=128, NX=128, M=12, DH=128, DIN=128
// Layout: h [b][c][t][x] fp32.
// Spectral conv uses only 24x12 = 288 modes -> direct factored DFTs.

#define NBATCH 16
#define HCH    64
#define NTT    128
#define NXX    128
#define MMODE  12
#define KTN    24
#define NMODE  288   // KTN*MMODE

// ---------------- tables ----------------
// Tf_x [12][128] float2 = (cos, -sin) of 2*pi*kx*x/128   (forward over x)
// Tf_t [24][128] float2 = (cos, -sin) of 2*pi*f*t/128, f = kti<12?kti:kti+104
// Ti_t [24][128] float2 = (cos, +sin)                     (inverse over t)
// Ti_x [12][128] float2 = w(kx)/16384 * (cos, +sin)       (inverse over x, weights folded)
__global__ __launch_bounds__(256) void k_tables(float* Tf_x, float* Tf_t, float* Ti_t, float* Ti_x) {
    int tid = threadIdx.x;
    const float STEP = 6.2831853071795864769f / 128.0f;
    for (int i = tid; i < 12 * 128; i += 256) {
        int kx = i >> 7, x = i & 127;
        int r = (kx * x) & 127;
        float th = r * STEP;
        float c = cosf(th), s = sinf(th);
        Tf_x[2 * i] = c; Tf_x[2 * i + 1] = -s;
        float w = (kx == 0 ? 1.0f : 2.0f) / 16384.0f;
        Ti_x[2 * i] = w * c; Ti_x[2 * i + 1] = w * s;
    }
    for (int i = tid; i < 24 * 128; i += 256) {
        int kti = i >> 7, t = i & 127;
        int f = (kti < 12) ? kti : (kti + 104);   // 116..127
        int r = (f * t) & 127;
        float th = r * STEP;
        float c = cosf(th), s = sinf(th);
        Tf_t[2 * i] = c; Tf_t[2 * i + 1] = -s;
        Ti_t[2 * i] = c; Ti_t[2 * i + 1] = s;
    }
}

// ---------------- fc0 ----------------
// U[b][c] = fc0_b[c] + sum_d u0[b,d]*fc0_w[c, 2+d]
__global__ void k_u(const float* __restrict__ u0, const float* __restrict__ w,
                    const float* __restrict__ bias, float* __restrict__ U) {
    int b = blockIdx.x, c = threadIdx.x;
    float acc = bias[c];
    const float* wr = w + c * 130 + 2;
    const float* ur = u0 + b * 128;
    for (int d = 0; d < 128; ++d) acc += ur[d] * wr[d];
    U[b * 64 + c] = acc;
}

// h[b][c][t][x] = x[x]*w[c][0] + t[t]*w[c][1] + U[b][c]
__global__ __launch_bounds__(256) void k_fc0(const float* __restrict__ xs, const float* __restrict__ ts,
                                             const float* __restrict__ w, const float* __restrict__ U,
                                             float* __restrict__ h) {
    int idx = blockIdx.x * 256 + threadIdx.x;      // float4 index over 16*64*128*32
    int x4 = idx & 31;
    int t  = (idx >> 5) & 127;
    int c  = (idx >> 12) & 63;
    int b  = idx >> 18;
    float w0 = w[c * 130];
    float base = ts[t] * w[c * 130 + 1] + U[b * 64 + c];
    float4 xv = reinterpret_cast<const float4*>(xs)[x4];
    float4 o;
    o.x = xv.x * w0 + base; o.y = xv.y * w0 + base;
    o.z = xv.z * w0 + base; o.w = xv.w * w0 + base;
    reinterpret_cast<float4*>(h)[idx] = o;
}

// ---------------- weight pre-transpose ----------------
// Wt[l][gmode][c][o] float2, gmode = kti*12+kx (kti<12 from w1, else w2)
__global__ __launch_bounds__(256) void k_wt(const float* __restrict__ w1re, const float* __restrict__ w1im,
                                            const float* __restrict__ w2re, const float* __restrict__ w2im,
                                            float2* __restrict__ Wt) {
    __shared__ float ldsre[32 * 145];
    __shared__ float ldsim[32 * 145];
    int bid = blockIdx.x, tid = threadIdx.x;
    int c = bid & 63, tbl = (bid >> 6) & 1, l = bid >> 7;
    const float* re = (tbl ? w2re : w1re) + (size_t)((l * 64 + c) * 64) * 144;
    const float* im = (tbl ? w2im : w1im) + (size_t)((l * 64 + c) * 64) * 144;
    int moff = tbl * 144;
    for (int half = 0; half < 2; ++half) {
        __syncthreads();
        for (int i = tid; i < 32 * 144; i += 256) {
            int o = i / 144, m = i - o * 144;
            ldsre[o * 145 + m] = re[(half * 32 + o) * 144 + m];
            ldsim[o * 145 + m] = im[(half * 32 + o) * 144 + m];
        }
        __syncthreads();
        for (int i = tid; i < 32 * 144; i += 256) {
            int mode = i >> 5, o = i & 31;
            Wt[((size_t)(l * 288 + moff + mode) * 64 + c) * 64 + half * 32 + o] =
                make_float2(ldsre[o * 145 + mode], ldsim[o * 145 + mode]);
        }
    }
}

// ---------------- forward DFT over x ----------------
// A[row][kx] = sum_x h[row][x] * e^{-2pi i kx x/128}; row = (b*64+c)*128+t
__global__ __launch_bounds__(256) void k_dftx(const float* __restrict__ h, const float* __restrict__ Tf_x,
                                              float2* __restrict__ A) {
    __shared__ float  ht[64 * 130];
    __shared__ float2 tf[12 * 129];
    int blk = blockIdx.x, tid = threadIdx.x;
    const float* src = h + (size_t)blk * 64 * 128;
    for (int i = tid; i < 64 * 128; i += 256) {
        int r = i >> 7, x = i & 127;
        ht[r * 130 + x] = src[i];
    }
    const float2* tfg = (const float2*)Tf_x;
    for (int i = tid; i < 12 * 128; i += 256) {
        int kx = i >> 7, x = i & 127;
        tf[kx * 129 + x] = tfg[i];
    }
    __syncthreads();
    float2* dst = A + (size_t)blk * 64 * 12;
#pragma unroll
    for (int k = 0; k < 3; ++k) {
        int oi = tid + k * 256;             // 0..767
        int r = oi / 12, kx = oi - r * 12;
        float ar = 0.f, ai = 0.f;
        const float*  hp = ht + r * 130;
        const float2* tp = tf + kx * 129;
#pragma unroll 4
        for (int x = 0; x < 128; ++x) {
            float v = hp[x];
            float2 wv = tp[x];
            ar += v * wv.x; ai += v * wv.y;
        }
        dst[oi] = make_float2(ar, ai);
    }
}

// ---------------- forward DFT over t ----------------
// Hm[mode][b][c] = sum_t A[b][c][t][kx] * e^{-2pi i f t/128}
__global__ __launch_bounds__(256) void k_dftt(const float2* __restrict__ A, const float* __restrict__ Tf_t,
                                              float2* __restrict__ Hm) {
    __shared__ float2 al[128 * 12];
    __shared__ float2 tt[24 * 129];
    int bc = blockIdx.x, tid = threadIdx.x;
    const float2* src = A + (size_t)bc * 128 * 12;
    for (int i = tid; i < 128 * 12; i += 256) al[i] = src[i];
    const float2* tg = (const float2*)Tf_t;
    for (int i = tid; i < 24 * 128; i += 256) {
        int kt = i >> 7, t = i & 127;
        tt[kt * 129 + t] = tg[i];
    }
    __syncthreads();
    int b = bc >> 6, c = bc & 63;
    for (int oi = tid; oi < 288; oi += 256) {
        int kt = oi / 12, kx = oi - kt * 12;
        float hr = 0.f, hi = 0.f;
        const float2* tp = tt + kt * 129;
#pragma unroll 4
        for (int t = 0; t < 128; ++t) {
            float2 a = al[t * 12 + kx];
            float2 wv = tp[t];
            hr += a.x * wv.x - a.y * wv.y;
            hi += a.x * wv.y + a.y * wv.x;
        }
        Hm[((size_t)oi * 16 + b) * 64 + c] = make_float2(hr, hi);
    }
}

// ---------------- per-mode channel mix ----------------
// Om[b][o][mode] = sum_c Hm[mode][b][c] * WtL[mode][c][o]  (complex)
__global__ __launch_bounds__(256) void k_mix(const float2* __restrict__ Hm, const float2* __restrict__ WtL,
                                             float2* __restrict__ Om) {
    __shared__ float2 hl[8 * 64];
    int bid = blockIdx.x, tid = threadIdx.x;
    int mode = bid >> 1, bh = bid & 1;
    const float2* hsrc = Hm + ((size_t)mode * 16 + bh * 8) * 64;
    for (int i = tid; i < 512; i += 256) hl[i] = hsrc[i];
    __syncthreads();
    int o = tid & 63, bg = tid >> 6;
    const float2* wp = WtL + (size_t)mode * 4096 + o;
    const float2* h0 = hl + (bg * 2) * 64;
    const float2* h1 = hl + (bg * 2 + 1) * 64;
    float a0r = 0.f, a0i = 0.f, a1r = 0.f, a1i = 0.f;
#pragma unroll 4
    for (int c = 0; c < 64; ++c) {
        float2 wv = wp[c * 64];
        float2 a0 = h0[c], a1 = h1[c];
        a0r += a0.x * wv.x - a0.y * wv.y;
        a0i += a0.x * wv.y + a0.y * wv.x;
        a1r += a1.x * wv.x - a1.y * wv.y;
        a1i += a1.x * wv.y + a1.y * wv.x;
    }
    int b0 = bh * 8 + bg * 2;
    Om[((size_t)(b0)*64 + o) * 288 + mode]     = make_float2(a0r, a0i);
    Om[((size_t)(b0 + 1) * 64 + o) * 288 + mode] = make_float2(a1r, a1i);
}

// fallback without pre-transposed weights (strided reads)
__global__ __launch_bounds__(256) void k_mix_raw(const float2* __restrict__ Hm,
                                                 const float* __restrict__ w1re, const float* __restrict__ w1im,
                                                 const float* __restrict__ w2re, const float* __restrict__ w2im,
                                                 float2* __restrict__ Om) {
    __shared__ float2 hl[8 * 64];
    int bid = blockIdx.x, tid = threadIdx.x;
    int mode = bid >> 1, bh = bid & 1;
    const float2* hsrc = Hm + ((size_t)mode * 16 + bh * 8) * 64;
    for (int i = tid; i < 512; i += 256) hl[i] = hsrc[i];
    __syncthreads();
    int kti = mode / 12, kx = mode - kti * 12;
    const float* re; const float* im; int ktw;
    if (kti < 12) { re = w1re; im = w1im; ktw = kti; }
    else          { re = w2re; im = w2im; ktw = kti - 12; }
    int off = ktw * 12 + kx;
    int o = tid & 63, bg = tid >> 6;
    const float2* h0 = hl + (bg * 2) * 64;
    const float2* h1 = hl + (bg * 2 + 1) * 64;
    float a0r = 0.f, a0i = 0.f, a1r = 0.f, a1i = 0.f;
    for (int c = 0; c < 64; ++c) {
        size_t widx = (size_t)(c * 64 + o) * 144 + off;
        float wr = re[widx], wi = im[widx];
        float2 a0 = h0[c], a1 = h1[c];
        a0r += a0.x * wr - a0.y * wi;
        a0i += a0.x * wi + a0.y * wr;
        a1r += a1.x * wr - a1.y * wi;
        a1i += a1.x * wi + a1.y * wr;
    }
    int b0 = bh * 8 + bg * 2;
    Om[((size_t)(b0)*64 + o) * 288 + mode]       = make_float2(a0r, a0i);
    Om[((size_t)(b0 + 1) * 64 + o) * 288 + mode] = make_float2(a1r, a1i);
}

// ---------------- inverse DFT over t ----------------
// B[b][o][t][kx] = sum_kt Om[b][o][kt*12+kx] * e^{+2pi i f t/128}
__global__ __launch_bounds__(256) void k_idftt(const float2* __restrict__ Om, const float* __restrict__ Ti_t,
                                               float2* __restrict__ B) {
    __shared__ float2 ol[288];
    __shared__ float2 tt[24 * 129];
    int bo = blockIdx.x, tid = threadIdx.x;
    const float2* src = Om + (size_t)bo * 288;
    for (int i = tid; i < 288; i += 256) ol[i] = src[i];
    const float2* tg = (const float2*)Ti_t;
    for (int i = tid; i < 24 * 128; i += 256) {
        int kt = i >> 7, t = i & 127;
        tt[kt * 129 + t] = tg[i];
    }
    __syncthreads();
    float2* dst = B + (size_t)bo * 128 * 12;
#pragma unroll
    for (int k = 0; k < 6; ++k) {
        int oi = tid + k * 256;                 // 0..1535
        int t = oi / 12, kx = oi - t * 12;
        float br = 0.f, bi = 0.f;
#pragma unroll
        for (int kt = 0; kt < 24; ++kt) {
            float2 a = ol[kt * 12 + kx];
            float2 wv = tt[kt * 129 + t];
            br += a.x * wv.x - a.y * wv.y;
            bi += a.x * wv.y + a.y * wv.x;
        }
        dst[oi] = make_float2(br, bi);
    }
}

// ---------------- fused pointwise conv + inverse DFT over x + bias + gelu (in-place) ----------------
template <int DOGELU>
__global__ __launch_bounds__(256) void k_conv_idftx(float* __restrict__ h, const float2* __restrict__ B,
                                                    const float* __restrict__ wconv, const float* __restrict__ bconv,
                                                    const float* __restrict__ Ti_x) {
    __shared__ float  hs[64 * 66];   // [x][c]
    __shared__ float  ws[64 * 66];   // [o][c]
    __shared__ float2 Bs[64 * 12];   // [o][kx]
    __shared__ float2 Ts[12 * 64];   // [kx][x]
    int bid = blockIdx.x, tid = threadIdx.x;
    int xh = bid & 1, t = (bid >> 1) & 127, b = bid >> 8;
    float* hb = h + ((size_t)(b * 64) * 128 + t) * 128 + xh * 64;   // + c*16384 per channel
    for (int i = tid; i < 64 * 64; i += 256) {
        int c = i >> 6, x = i & 63;
        hs[x * 66 + c] = hb[(size_t)c * 16384 + x];
    }
    for (int i = tid; i < 64 * 64; i += 256) {
        int o = i >> 6, c = i & 63;
        ws[o * 66 + c] = wconv[o * 64 + c];
    }
    const float2* bsrc = B + ((size_t)(b * 64) * 128 + t) * 12;
    for (int i = tid; i < 64 * 12; i += 256) {
        int o = i / 12, kx = i - o * 12;
        Bs[i] = bsrc[(size_t)o * 128 * 12 + kx];
    }
    const float2* tg = (const float2*)Ti_x;
    for (int i = tid; i < 12 * 64; i += 256) {
        int kx = i >> 6, x = i & 63;
        Ts[i] = tg[kx * 128 + xh * 64 + x];
    }
    __syncthreads();
    int x4 = tid & 15;
    int o4 = tid >> 4;
    float acc[4][4];
#pragma unroll
    for (int i = 0; i < 4; ++i)
#pragma unroll
        for (int j = 0; j < 4; ++j) acc[i][j] = 0.f;
    for (int c = 0; c < 64; c += 2) {
        float2 hv[4], wv[4];
#pragma unroll
        for (int j = 0; j < 4; ++j) hv[j] = *(const float2*)&hs[(x4 + 16 * j) * 66 + c];
#pragma unroll
        for (int i = 0; i < 4; ++i) wv[i] = *(const float2*)&ws[(o4 + 16 * i) * 66 + c];
#pragma unroll
        for (int i = 0; i < 4; ++i)
#pragma unroll
            for (int j = 0; j < 4; ++j)
                acc[i][j] += wv[i].x * hv[j].x + wv[i].y * hv[j].y;
    }
#pragma unroll
    for (int kx = 0; kx < 12; ++kx) {
        float2 bv[4], tv[4];
#pragma unroll
        for (int i = 0; i < 4; ++i) bv[i] = Bs[(o4 + 16 * i) * 12 + kx];
#pragma unroll
        for (int j = 0; j < 4; ++j) tv[j] = Ts[kx * 64 + x4 + 16 * j];
#pragma unroll
        for (int i = 0; i < 4; ++i)
#pragma unroll
            for (int j = 0; j < 4; ++j)
                acc[i][j] += bv[i].x * tv[j].x - bv[i].y * tv[j].y;
    }
#pragma unroll
    for (int i = 0; i < 4; ++i) {
        int o = o4 + 16 * i;
        float bc = bconv[o];
#pragma unroll
        for (int j = 0; j < 4; ++j) {
            float v = acc[i][j] + bc;
            if (DOGELU) v = 0.5f * v * (1.0f + erff(v * 0.70710678118654752f));
            hb[(size_t)o * 16384 + x4 + 16 * j] = v;
        }
    }
}

// ---------------- head: fc1 + gelu + fc2 ----------------
__global__ __launch_bounds__(256) void k_head(const float* __restrict__ h, const float* __restrict__ w1,
                                              const float* __restrict__ b1, const float* __restrict__ w2,
                                              const float* __restrict__ b2, float* __restrict__ out) {
    __shared__ float hs[64 * 66];     // [x][c]
    __shared__ float w1s[128 * 66];   // [d][c]
    __shared__ float red[4 * 64];
    __shared__ float w2s[128], b1s[128];
    int bid = blockIdx.x, tid = threadIdx.x;
    int xh = bid & 1, t = (bid >> 1) & 127, b = bid >> 8;
    const float* hb = h + ((size_t)(b * 64) * 128 + t) * 128 + xh * 64;
    for (int i = tid; i < 64 * 64; i += 256) {
        int c = i >> 6, x = i & 63;
        hs[x * 66 + c] = hb[(size_t)c * 16384 + x];
    }
    for (int i = tid; i < 128 * 64; i += 256) {
        int d = i >> 6, c = i & 63;
        w1s[d * 66 + c] = w1[i];
    }
    if (tid < 128) { w2s[tid] = w2[tid]; b1s[tid] = b1[tid]; }
    __syncthreads();
    int x = tid & 63, dg = tid >> 6;
    float partial = 0.f;
    for (int k = 0; k < 32; ++k) {
        int d = dg * 32 + k;
        float acc = b1s[d];
        const float* hp = hs + x * 66;
        const float* wp = w1s + d * 66;
#pragma unroll 8
        for (int c = 0; c < 64; c += 2) {
            float2 hv = *(const float2*)&hp[c];
            float2 wv = *(const float2*)&wp[c];
            acc += hv.x * wv.x + hv.y * wv.y;
        }
        float y = 0.5f * acc * (1.0f + erff(acc * 0.70710678118654752f));
        partial += y * w2s[d];
    }
    red[dg * 64 + x] = partial;
    __syncthreads();
    if (dg == 0) {
        float r = red[x] + red[64 + x] + red[128 + x] + red[192 + x] + b2[0];
        out[((size_t)b * 128 + t) * 128 + xh * 64 + x] = r;
    }
}

extern "C" void kernel_launch(void* const* d_in, const int* in_sizes, int n_in,
                              void* d_out, int out_size, void* d_ws, size_t ws_size,
                              hipStream_t stream) {
    const float* ts    = (const float*)d_in[0];
    const float* xs    = (const float*)d_in[1];
    const float* u0    = (const float*)d_in[2];
    const float* fc0_w = (const float*)d_in[3];
    const float* fc0_b = (const float*)d_in[4];
    const float* w1re  = (const float*)d_in[5];
    const float* w1im  = (const float*)d_in[6];
    const float* w2re  = (const float*)d_in[7];
    const float* w2im  = (const float*)d_in[8];
    const float* wconv = (const float*)d_in[9];
    const float* bconv = (const float*)d_in[10];
    const float* fc1w  = (const float*)d_in[11];
    const float* fc1b  = (const float*)d_in[12];
    const float* fc2w  = (const float*)d_in[13];
    const float* fc2b  = (const float*)d_in[14];
    float* out = (float*)d_out;

    char* ws = (char*)d_ws;
    size_t off = 0;
    auto alloc = [&](size_t bytes) -> char* {
        char* p = ws + off;
        off = (off + bytes + 255) & ~(size_t)255;
        return p;
    };
    float*  h    = (float*)alloc(67108864);          // [16][64][128][128]
    float2* A    = (float2*)alloc(12582912);         // [16*64*128][12]
    float2* Hm   = (float2*)alloc(2359296);          // [288][16][64]
    float2* Om   = (float2*)alloc(2359296);          // [16][64][288]
    float2* Bv   = (float2*)alloc(12582912);         // [16*64][128][12]
    float*  U    = (float*)alloc(4096);              // [16][64]
    float*  Tf_x = (float*)alloc(12288);
    float*  Tf_t = (float*)alloc(24576);
    float*  Ti_t = (float*)alloc(24576);
    float*  Ti_x = (float*)alloc(12288);
    size_t base_need = off;
    if (ws_size < base_need) return;                 // cannot run safely
    float2* Wt = (float2*)alloc(37748736);           // [4][288][64][64] float2
    bool use_wt = (ws_size >= off);

    k_tables<<<1, 256, 0, stream>>>(Tf_x, Tf_t, Ti_t, Ti_x);
    k_u<<<16, 64, 0, stream>>>(u0, fc0_w, fc0_b, U);
    k_fc0<<<16384, 256, 0, stream>>>(xs, ts, fc0_w, U, h);
    if (use_wt)
        k_wt<<<512, 256, 0, stream>>>(w1re, w1im, w2re, w2im, Wt);

    for (int l = 0; l < 4; ++l) {
        k_dftx<<<2048, 256, 0, stream>>>(h, Tf_x, A);
        k_dftt<<<1024, 256, 0, stream>>>(A, Tf_t, Hm);
        if (use_wt)
            k_mix<<<576, 256, 0, stream>>>(Hm, Wt + (size_t)l * 288 * 4096, Om);
        else
            k_mix_raw<<<576, 256, 0, stream>>>(Hm, w1re + (size_t)l * 589824, w1im + (size_t)l * 589824,
                                               w2re + (size_t)l * 589824, w2im + (size_t)l * 589824, Om);
        k_idftt<<<1024, 256, 0, stream>>>(Om, Ti_t, Bv);
        if (l < 3)
            k_conv_idftx<1><<<4096, 256, 0, stream>>>(h, Bv, wconv + l * 4096, bconv + l * 64, Ti_x);
        else
            k_conv_idftx<0><<<4096, 256, 0, stream>>>(h, Bv, wconv + l * 4096, bconv + l * 64, Ti_x);
    }
    k_head<<<4096, 256, 0, stream>>>(h, fc1w, fc1b, fc2w, fc2b, out);
}

// Round 2
// 839.459 us; speedup vs baseline: 1.3815x; 1.3815x over previous
//
#include <hip/hip_runtime.h>
#include <math.h>

// FNO: N=16, H=64, NT=128, NX=128, M=12, DH=128, DIN=128
// Layout: h [b][c][t][x] fp32.
// Spectral conv uses only 24x12 = 288 modes -> direct factored DFTs.

// ---------------- tables ----------------
// Tf_x [12][128] float2 = (cos, -sin) of 2*pi*kx*x/128   (forward over x)
// Tf_t [24][128] float2 = (cos, -sin) of 2*pi*f*t/128, f = kti<12?kti:kti+104
// Ti_t [24][128] float2 = (cos, +sin)                     (inverse over t)
// Ti_x [12][128] float2 = w(kx)/16384 * (cos, +sin)       (inverse over x, weights folded)
__global__ __launch_bounds__(256) void k_tables(float* Tf_x, float* Tf_t, float* Ti_t, float* Ti_x) {
    int tid = threadIdx.x;
    const float STEP = 6.2831853071795864769f / 128.0f;
    for (int i = tid; i < 12 * 128; i += 256) {
        int kx = i >> 7, x = i & 127;
        int r = (kx * x) & 127;
        float th = r * STEP;
        float c = cosf(th), s = sinf(th);
        Tf_x[2 * i] = c; Tf_x[2 * i + 1] = -s;
        float w = (kx == 0 ? 1.0f : 2.0f) / 16384.0f;
        Ti_x[2 * i] = w * c; Ti_x[2 * i + 1] = w * s;
    }
    for (int i = tid; i < 24 * 128; i += 256) {
        int kti = i >> 7, t = i & 127;
        int f = (kti < 12) ? kti : (kti + 104);   // 116..127
        int r = (f * t) & 127;
        float th = r * STEP;
        float c = cosf(th), s = sinf(th);
        Tf_t[2 * i] = c; Tf_t[2 * i + 1] = -s;
        Ti_t[2 * i] = c; Ti_t[2 * i + 1] = s;
    }
}

// ---------------- fc0 ----------------
__global__ void k_u(const float* __restrict__ u0, const float* __restrict__ w,
                    const float* __restrict__ bias, float* __restrict__ U) {
    int b = blockIdx.x, c = threadIdx.x;
    float acc = bias[c];
    const float* wr = w + c * 130 + 2;
    const float* ur = u0 + b * 128;
    for (int d = 0; d < 128; ++d) acc += ur[d] * wr[d];
    U[b * 64 + c] = acc;
}

__global__ __launch_bounds__(256) void k_fc0(const float* __restrict__ xs, const float* __restrict__ ts,
                                             const float* __restrict__ w, const float* __restrict__ U,
                                             float* __restrict__ h) {
    int idx = blockIdx.x * 256 + threadIdx.x;      // float4 index over 16*64*128*32
    int x4 = idx & 31;
    int t  = (idx >> 5) & 127;
    int c  = (idx >> 12) & 63;
    int b  = idx >> 18;
    float w0 = w[c * 130];
    float base = ts[t] * w[c * 130 + 1] + U[b * 64 + c];
    float4 xv = reinterpret_cast<const float4*>(xs)[x4];
    float4 o;
    o.x = xv.x * w0 + base; o.y = xv.y * w0 + base;
    o.z = xv.z * w0 + base; o.w = xv.w * w0 + base;
    reinterpret_cast<float4*>(h)[idx] = o;
}

// ---------------- weight pre-transpose ----------------
// Wt[l][gmode][c][o] float2, gmode = kti*12+kx (kti<12 from w1, else w2)
__global__ __launch_bounds__(256) void k_wt(const float* __restrict__ w1re, const float* __restrict__ w1im,
                                            const float* __restrict__ w2re, const float* __restrict__ w2im,
                                            float2* __restrict__ Wt) {
    __shared__ float ldsre[32 * 145];
    __shared__ float ldsim[32 * 145];
    int bid = blockIdx.x, tid = threadIdx.x;
    int c = bid & 63, tbl = (bid >> 6) & 1, l = bid >> 7;
    const float* re = (tbl ? w2re : w1re) + (size_t)((l * 64 + c) * 64) * 144;
    const float* im = (tbl ? w2im : w1im) + (size_t)((l * 64 + c) * 64) * 144;
    int moff = tbl * 144;
    for (int half = 0; half < 2; ++half) {
        __syncthreads();
        for (int i = tid; i < 32 * 144; i += 256) {
            int o = i / 144, m = i - o * 144;
            ldsre[o * 145 + m] = re[(half * 32 + o) * 144 + m];
            ldsim[o * 145 + m] = im[(half * 32 + o) * 144 + m];
        }
        __syncthreads();
        for (int i = tid; i < 32 * 144; i += 256) {
            int mode = i >> 5, o = i & 31;
            Wt[((size_t)(l * 288 + moff + mode) * 64 + c) * 64 + half * 32 + o] =
                make_float2(ldsre[o * 145 + mode], ldsim[o * 145 + mode]);
        }
    }
}

// ---------------- forward DFT over x (register-tiled) ----------------
// block: 64 rows (rows = (b*64+c)*128+t); 256 threads = 32 rowg x 8 colg
// thread: rows {rowg, rowg+32} x 3 real-cols (of 24 = 12 complex kx as re/im planes)
__global__ __launch_bounds__(256) void k_dftx(const float* __restrict__ h, const float* __restrict__ Tf_x,
                                              float2* __restrict__ A) {
    __shared__ float hs[64 * 130];
    __shared__ float tfs[24 * 130];
    int blk = blockIdx.x, tid = threadIdx.x;
    const float* src = h + (size_t)blk * 64 * 128;
    for (int i = tid; i < 64 * 128; i += 256) {
        int r = i >> 7, x = i & 127;
        hs[r * 130 + x] = src[i];
    }
    const float2* tfg = (const float2*)Tf_x;
    for (int i = tid; i < 12 * 128; i += 256) {
        int kx = i >> 7, x = i & 127;
        float2 v = tfg[i];
        tfs[(2 * kx) * 130 + x]     = v.x;   // re plane (cos)
        tfs[(2 * kx + 1) * 130 + x] = v.y;   // im plane (-sin)
    }
    __syncthreads();
    int rowg = tid & 31, colg = tid >> 5;       // colg 0..7, 3 cols each
    int cb = colg * 3;
    float acc0[3], acc1[3];
#pragma unroll
    for (int k = 0; k < 3; ++k) { acc0[k] = 0.f; acc1[k] = 0.f; }
    const float* h0 = hs + rowg * 130;
    const float* h1 = hs + (rowg + 32) * 130;
#pragma unroll 8
    for (int x = 0; x < 128; x += 2) {
        float2 a = *(const float2*)&h0[x];
        float2 b = *(const float2*)&h1[x];
#pragma unroll
        for (int k = 0; k < 3; ++k) {
            float2 tv = *(const float2*)&tfs[(cb + k) * 130 + x];
            acc0[k] += a.x * tv.x + a.y * tv.y;
            acc1[k] += b.x * tv.x + b.y * tv.y;
        }
    }
    // cols cb..cb+2: col even = re of kx=col/2, odd = im
    float* dst = (float*)(A + (size_t)blk * 64 * 12);
#pragma unroll
    for (int k = 0; k < 3; ++k) {
        dst[rowg * 24 + cb + k]        = acc0[k];
        dst[(rowg + 32) * 24 + cb + k] = acc1[k];
    }
}

// ---------------- forward DFT over t ----------------
__global__ __launch_bounds__(256) void k_dftt(const float2* __restrict__ A, const float* __restrict__ Tf_t,
                                              float2* __restrict__ Hm) {
    __shared__ float2 al[128 * 12];
    __shared__ float2 tt[24 * 129];
    int bc = blockIdx.x, tid = threadIdx.x;
    const float2* src = A + (size_t)bc * 128 * 12;
    for (int i = tid; i < 128 * 12; i += 256) al[i] = src[i];
    const float2* tg = (const float2*)Tf_t;
    for (int i = tid; i < 24 * 128; i += 256) {
        int kt = i >> 7, t = i & 127;
        tt[kt * 129 + t] = tg[i];
    }
    __syncthreads();
    int b = bc >> 6, c = bc & 63;
    for (int oi = tid; oi < 288; oi += 256) {
        int kt = oi / 12, kx = oi - kt * 12;
        float hr = 0.f, hi = 0.f;
        const float2* tp = tt + kt * 129;
#pragma unroll 4
        for (int t = 0; t < 128; ++t) {
            float2 a = al[t * 12 + kx];
            float2 wv = tp[t];
            hr += a.x * wv.x - a.y * wv.y;
            hi += a.x * wv.y + a.y * wv.x;
        }
        Hm[((size_t)oi * 16 + b) * 64 + c] = make_float2(hr, hi);
    }
}

// ---------------- per-mode channel mix ----------------
__global__ __launch_bounds__(256) void k_mix(const float2* __restrict__ Hm, const float2* __restrict__ WtL,
                                             float2* __restrict__ Om) {
    __shared__ float2 hl[8 * 64];
    int bid = blockIdx.x, tid = threadIdx.x;
    int mode = bid >> 1, bh = bid & 1;
    const float2* hsrc = Hm + ((size_t)mode * 16 + bh * 8) * 64;
    for (int i = tid; i < 512; i += 256) hl[i] = hsrc[i];
    __syncthreads();
    int o = tid & 63, bg = tid >> 6;
    const float2* wp = WtL + (size_t)mode * 4096 + o;
    const float2* h0 = hl + (bg * 2) * 64;
    const float2* h1 = hl + (bg * 2 + 1) * 64;
    float a0r = 0.f, a0i = 0.f, a1r = 0.f, a1i = 0.f;
#pragma unroll 4
    for (int c = 0; c < 64; ++c) {
        float2 wv = wp[c * 64];
        float2 a0 = h0[c], a1 = h1[c];
        a0r += a0.x * wv.x - a0.y * wv.y;
        a0i += a0.x * wv.y + a0.y * wv.x;
        a1r += a1.x * wv.x - a1.y * wv.y;
        a1i += a1.x * wv.y + a1.y * wv.x;
    }
    int b0 = bh * 8 + bg * 2;
    Om[((size_t)(b0)*64 + o) * 288 + mode]       = make_float2(a0r, a0i);
    Om[((size_t)(b0 + 1) * 64 + o) * 288 + mode] = make_float2(a1r, a1i);
}

__global__ __launch_bounds__(256) void k_mix_raw(const float2* __restrict__ Hm,
                                                 const float* __restrict__ w1re, const float* __restrict__ w1im,
                                                 const float* __restrict__ w2re, const float* __restrict__ w2im,
                                                 float2* __restrict__ Om) {
    __shared__ float2 hl[8 * 64];
    int bid = blockIdx.x, tid = threadIdx.x;
    int mode = bid >> 1, bh = bid & 1;
    const float2* hsrc = Hm + ((size_t)mode * 16 + bh * 8) * 64;
    for (int i = tid; i < 512; i += 256) hl[i] = hsrc[i];
    __syncthreads();
    int kti = mode / 12, kx = mode - kti * 12;
    const float* re; const float* im; int ktw;
    if (kti < 12) { re = w1re; im = w1im; ktw = kti; }
    else          { re = w2re; im = w2im; ktw = kti - 12; }
    int off = ktw * 12 + kx;
    int o = tid & 63, bg = tid >> 6;
    const float2* h0 = hl + (bg * 2) * 64;
    const float2* h1 = hl + (bg * 2 + 1) * 64;
    float a0r = 0.f, a0i = 0.f, a1r = 0.f, a1i = 0.f;
    for (int c = 0; c < 64; ++c) {
        size_t widx = (size_t)(c * 64 + o) * 144 + off;
        float wr = re[widx], wi = im[widx];
        float2 a0 = h0[c], a1 = h1[c];
        a0r += a0.x * wr - a0.y * wi;
        a0i += a0.x * wi + a0.y * wr;
        a1r += a1.x * wr - a1.y * wi;
        a1i += a1.x * wi + a1.y * wr;
    }
    int b0 = bh * 8 + bg * 2;
    Om[((size_t)(b0)*64 + o) * 288 + mode]       = make_float2(a0r, a0i);
    Om[((size_t)(b0 + 1) * 64 + o) * 288 + mode] = make_float2(a1r, a1i);
}

// ---------------- inverse DFT over t ----------------
__global__ __launch_bounds__(256) void k_idftt(const float2* __restrict__ Om, const float* __restrict__ Ti_t,
                                               float2* __restrict__ B) {
    __shared__ float2 ol[288];
    __shared__ float2 tt[24 * 129];
    int bo = blockIdx.x, tid = threadIdx.x;
    const float2* src = Om + (size_t)bo * 288;
    for (int i = tid; i < 288; i += 256) ol[i] = src[i];
    const float2* tg = (const float2*)Ti_t;
    for (int i = tid; i < 24 * 128; i += 256) {
        int kt = i >> 7, t = i & 127;
        tt[kt * 129 + t] = tg[i];
    }
    __syncthreads();
    float2* dst = B + (size_t)bo * 128 * 12;
#pragma unroll
    for (int k = 0; k < 6; ++k) {
        int oi = tid + k * 256;                 // 0..1535
        int t = oi / 12, kx = oi - t * 12;
        float br = 0.f, bi = 0.f;
#pragma unroll
        for (int kt = 0; kt < 24; ++kt) {
            float2 a = ol[kt * 12 + kx];
            float2 wv = tt[kt * 129 + t];
            br += a.x * wv.x - a.y * wv.y;
            bi += a.x * wv.y + a.y * wv.x;
        }
        dst[oi] = make_float2(br, bi);
    }
}

// ---------------- fused pointwise conv + inverse DFT over x + bias + gelu ----------------
// block = (b,t): full 128-x row, 64 o. 256 threads = 16 tx * 16 to.
// thread tile: 4 o (to+16i) x 8 x (tx+16j).
template <int DOGELU>
__global__ __launch_bounds__(256) void k_conv_idftx(float* __restrict__ h, const float2* __restrict__ B,
                                                    const float* __restrict__ wconv, const float* __restrict__ bconv,
                                                    const float* __restrict__ Ti_x) {
    __shared__ float  hs[128 * 66];   // [x][c]
    __shared__ float  ws[64 * 66];    // [o][c]
    __shared__ float2 Bs[64 * 12];    // [o][kx]
    __shared__ float2 Ts[12 * 128];   // [kx][x]
    int bid = blockIdx.x, tid = threadIdx.x;
    int t = bid & 127, b = bid >> 7;
    float* hb = h + ((size_t)(b * 64) * 128 + t) * 128;   // + c*16384 per channel
    for (int i = tid; i < 64 * 128; i += 256) {
        int c = i >> 7, x = i & 127;
        hs[x * 66 + c] = hb[(size_t)c * 16384 + x];
    }
    for (int i = tid; i < 64 * 64; i += 256) {
        ws[(i >> 6) * 66 + (i & 63)] = wconv[i];
    }
    const float2* bsrc = B + ((size_t)(b * 64) * 128 + t) * 12;
    for (int i = tid; i < 64 * 12; i += 256) {
        int o = i / 12, kx = i - o * 12;
        Bs[i] = bsrc[(size_t)o * 1536 + kx];
    }
    const float2* tg = (const float2*)Ti_x;
    for (int i = tid; i < 12 * 128; i += 256) Ts[i] = tg[i];
    __syncthreads();
    int tx = tid & 15, to = tid >> 4;
    float acc[4][8];
#pragma unroll
    for (int i = 0; i < 4; ++i)
#pragma unroll
        for (int j = 0; j < 8; ++j) acc[i][j] = 0.f;
    for (int c = 0; c < 64; c += 2) {
        float2 hv[8], wv[4];
#pragma unroll
        for (int j = 0; j < 8; ++j) hv[j] = *(const float2*)&hs[(tx + 16 * j) * 66 + c];
#pragma unroll
        for (int i = 0; i < 4; ++i) wv[i] = *(const float2*)&ws[(to + 16 * i) * 66 + c];
#pragma unroll
        for (int i = 0; i < 4; ++i)
#pragma unroll
            for (int j = 0; j < 8; ++j)
                acc[i][j] += wv[i].x * hv[j].x + wv[i].y * hv[j].y;
    }
#pragma unroll 4
    for (int kx = 0; kx < 12; ++kx) {
        float2 bv[4], tv[8];
#pragma unroll
        for (int i = 0; i < 4; ++i) bv[i] = Bs[(to + 16 * i) * 12 + kx];
#pragma unroll
        for (int j = 0; j < 8; ++j) tv[j] = Ts[kx * 128 + tx + 16 * j];
#pragma unroll
        for (int i = 0; i < 4; ++i)
#pragma unroll
            for (int j = 0; j < 8; ++j)
                acc[i][j] += bv[i].x * tv[j].x - bv[i].y * tv[j].y;
    }
#pragma unroll
    for (int i = 0; i < 4; ++i) {
        int o = to + 16 * i;
        float bc = bconv[o];
#pragma unroll
        for (int j = 0; j < 8; ++j) {
            float v = acc[i][j] + bc;
            if (DOGELU) v = 0.5f * v * (1.0f + erff(v * 0.70710678118654752f));
            hb[(size_t)o * 16384 + tx + 16 * j] = v;
        }
    }
}

// ---------------- head: fc1 + gelu + fc2 ----------------
// block = (b,t): 128 x, 128 d. 256 threads = 16 tx * 16 td; thread 8d x 8x.
__global__ __launch_bounds__(256) void k_head(const float* __restrict__ h, const float* __restrict__ w1,
                                              const float* __restrict__ b1, const float* __restrict__ w2,
                                              const float* __restrict__ b2, float* __restrict__ out) {
    __shared__ float hs[128 * 66];    // [x][c]
    __shared__ float w1s[128 * 66];   // [d][c]
    __shared__ float red[16 * 130];
    __shared__ float w2s[128], b1s[128];
    int bid = blockIdx.x, tid = threadIdx.x;
    int t = bid & 127, b = bid >> 7;
    const float* hb = h + ((size_t)(b * 64) * 128 + t) * 128;
    for (int i = tid; i < 64 * 128; i += 256) {
        int c = i >> 7, x = i & 127;
        hs[x * 66 + c] = hb[(size_t)c * 16384 + x];
    }
    for (int i = tid; i < 128 * 64; i += 256) {
        w1s[(i >> 6) * 66 + (i & 63)] = w1[i];
    }
    if (tid < 128) { w2s[tid] = w2[tid]; b1s[tid] = b1[tid]; }
    __syncthreads();
    int tx = tid & 15, td = tid >> 4;
    float acc[8][8];
#pragma unroll
    for (int i = 0; i < 8; ++i)
#pragma unroll
        for (int j = 0; j < 8; ++j) acc[i][j] = 0.f;
    for (int c = 0; c < 64; c += 2) {
        float2 hv[8], wv[8];
#pragma unroll
        for (int j = 0; j < 8; ++j) hv[j] = *(const float2*)&hs[(tx + 16 * j) * 66 + c];
#pragma unroll
        for (int i = 0; i < 8; ++i) wv[i] = *(const float2*)&w1s[(td + 16 * i) * 66 + c];
#pragma unroll
        for (int i = 0; i < 8; ++i)
#pragma unroll
            for (int j = 0; j < 8; ++j)
                acc[i][j] += wv[i].x * hv[j].x + wv[i].y * hv[j].y;
    }
    float p[8];
#pragma unroll
    for (int j = 0; j < 8; ++j) p[j] = 0.f;
#pragma unroll
    for (int i = 0; i < 8; ++i) {
        int d = td + 16 * i;
        float bb = b1s[d], wk = w2s[d];
#pragma unroll
        for (int j = 0; j < 8; ++j) {
            float v = acc[i][j] + bb;
            float g = 0.5f * v * (1.0f + erff(v * 0.70710678118654752f));
            p[j] += g * wk;
        }
    }
#pragma unroll
    for (int j = 0; j < 8; ++j) red[td * 130 + tx + 16 * j] = p[j];
    __syncthreads();
    if (tid < 128) {
        int x = tid;
        float s = 0.f;
#pragma unroll
        for (int g = 0; g < 16; ++g) s += red[g * 130 + x];
        out[((size_t)b * 128 + t) * 128 + x] = s + b2[0];
    }
}

extern "C" void kernel_launch(void* const* d_in, const int* in_sizes, int n_in,
                              void* d_out, int out_size, void* d_ws, size_t ws_size,
                              hipStream_t stream) {
    const float* ts    = (const float*)d_in[0];
    const float* xs    = (const float*)d_in[1];
    const float* u0    = (const float*)d_in[2];
    const float* fc0_w = (const float*)d_in[3];
    const float* fc0_b = (const float*)d_in[4];
    const float* w1re  = (const float*)d_in[5];
    const float* w1im  = (const float*)d_in[6];
    const float* w2re  = (const float*)d_in[7];
    const float* w2im  = (const float*)d_in[8];
    const float* wconv = (const float*)d_in[9];
    const float* bconv = (const float*)d_in[10];
    const float* fc1w  = (const float*)d_in[11];
    const float* fc1b  = (const float*)d_in[12];
    const float* fc2w  = (const float*)d_in[13];
    const float* fc2b  = (const float*)d_in[14];
    float* out = (float*)d_out;

    char* ws = (char*)d_ws;
    size_t off = 0;
    auto alloc = [&](size_t bytes) -> char* {
        char* p = ws + off;
        off = (off + bytes + 255) & ~(size_t)255;
        return p;
    };
    float*  h    = (float*)alloc(67108864);          // [16][64][128][128]
    float2* A    = (float2*)alloc(12582912);         // [16*64*128][12]
    float2* Hm   = (float2*)alloc(2359296);          // [288][16][64]
    float2* Om   = (float2*)alloc(2359296);          // [16][64][288]
    float2* Bv   = (float2*)alloc(12582912);         // [16*64][128][12]
    float*  U    = (float*)alloc(4096);              // [16][64]
    float*  Tf_x = (float*)alloc(12288);
    float*  Tf_t = (float*)alloc(24576);
    float*  Ti_t = (float*)alloc(24576);
    float*  Ti_x = (float*)alloc(12288);
    size_t base_need = off;
    if (ws_size < base_need) return;                 // cannot run safely
    float2* Wt = (float2*)alloc(37748736);           // [4][288][64][64] float2
    bool use_wt = (ws_size >= off);

    k_tables<<<1, 256, 0, stream>>>(Tf_x, Tf_t, Ti_t, Ti_x);
    k_u<<<16, 64, 0, stream>>>(u0, fc0_w, fc0_b, U);
    k_fc0<<<16384, 256, 0, stream>>>(xs, ts, fc0_w, U, h);
    if (use_wt)
        k_wt<<<512, 256, 0, stream>>>(w1re, w1im, w2re, w2im, Wt);

    for (int l = 0; l < 4; ++l) {
        k_dftx<<<2048, 256, 0, stream>>>(h, Tf_x, A);
        k_dftt<<<1024, 256, 0, stream>>>(A, Tf_t, Hm);
        if (use_wt)
            k_mix<<<576, 256, 0, stream>>>(Hm, Wt + (size_t)l * 288 * 4096, Om);
        else
            k_mix_raw<<<576, 256, 0, stream>>>(Hm, w1re + (size_t)l * 589824, w1im + (size_t)l * 589824,
                                               w2re + (size_t)l * 589824, w2im + (size_t)l * 589824, Om);
        k_idftt<<<1024, 256, 0, stream>>>(Om, Ti_t, Bv);
        if (l < 3)
            k_conv_idftx<1><<<2048, 256, 0, stream>>>(h, Bv, wconv + l * 4096, bconv + l * 64, Ti_x);
        else
            k_conv_idftx<0><<<2048, 256, 0, stream>>>(h, Bv, wconv + l * 4096, bconv + l * 64, Ti_x);
    }
    k_head<<<2048, 256, 0, stream>>>(h, fc1w, fc1b, fc2w, fc2b, out);
}

// Round 3
// 752.460 us; speedup vs baseline: 1.5412x; 1.1156x over previous
//
#include <hip/hip_runtime.h>
#include <math.h>

// FNO: N=16, H=64, NT=128, NX=128, M=12, DH=128, DIN=128
// h layout [b][c][t][x] fp32. Spectral conv: 24x12=288 modes, factored DFTs.
// Round 3: conv + head via split-bf16 MFMA (hi/lo, 3 pairings).

typedef __attribute__((ext_vector_type(8))) short short8;
typedef __attribute__((ext_vector_type(4))) float f32x4;

__device__ inline unsigned short bf16rn(float v) {
    unsigned int b = __float_as_uint(v);
    return (unsigned short)((b + 0x7FFFu + ((b >> 16) & 1u)) >> 16);
}
__device__ inline void split2(float v, unsigned short& h, unsigned short& l) {
    h = bf16rn(v);
    float hf = __uint_as_float((unsigned int)h << 16);
    l = bf16rn(v - hf);
}

// ---------------- tables ----------------
__global__ __launch_bounds__(256) void k_tables(float* Tf_x, float* Tf_t, float* Ti_t, float* Ti_x) {
    int tid = threadIdx.x;
    const float STEP = 6.2831853071795864769f / 128.0f;
    for (int i = tid; i < 12 * 128; i += 256) {
        int kx = i >> 7, x = i & 127;
        int r = (kx * x) & 127;
        float th = r * STEP;
        float c = cosf(th), s = sinf(th);
        Tf_x[2 * i] = c; Tf_x[2 * i + 1] = -s;
        float w = (kx == 0 ? 1.0f : 2.0f) / 16384.0f;
        Ti_x[2 * i] = w * c; Ti_x[2 * i + 1] = w * s;
    }
    for (int i = tid; i < 24 * 128; i += 256) {
        int kti = i >> 7, t = i & 127;
        int f = (kti < 12) ? kti : (kti + 104);
        int r = (f * t) & 127;
        float th = r * STEP;
        float c = cosf(th), s = sinf(th);
        Tf_t[2 * i] = c; Tf_t[2 * i + 1] = -s;
        Ti_t[2 * i] = c; Ti_t[2 * i + 1] = s;
    }
}

// ---------------- fc0 ----------------
__global__ void k_u(const float* __restrict__ u0, const float* __restrict__ w,
                    const float* __restrict__ bias, float* __restrict__ U) {
    int b = blockIdx.x, c = threadIdx.x;
    float acc = bias[c];
    const float* wr = w + c * 130 + 2;
    const float* ur = u0 + b * 128;
    for (int d = 0; d < 128; ++d) acc += ur[d] * wr[d];
    U[b * 64 + c] = acc;
}

__global__ __launch_bounds__(256) void k_fc0(const float* __restrict__ xs, const float* __restrict__ ts,
                                             const float* __restrict__ w, const float* __restrict__ U,
                                             float* __restrict__ h) {
    int idx = blockIdx.x * 256 + threadIdx.x;
    int x4 = idx & 31;
    int t  = (idx >> 5) & 127;
    int c  = (idx >> 12) & 63;
    int b  = idx >> 18;
    float w0 = w[c * 130];
    float base = ts[t] * w[c * 130 + 1] + U[b * 64 + c];
    float4 xv = reinterpret_cast<const float4*>(xs)[x4];
    float4 o;
    o.x = xv.x * w0 + base; o.y = xv.y * w0 + base;
    o.z = xv.z * w0 + base; o.w = xv.w * w0 + base;
    reinterpret_cast<float4*>(h)[idx] = o;
}

// ---------------- weight pre-transpose (for fp32 k_mix) ----------------
__global__ __launch_bounds__(256) void k_wt(const float* __restrict__ w1re, const float* __restrict__ w1im,
                                            const float* __restrict__ w2re, const float* __restrict__ w2im,
                                            float2* __restrict__ Wt) {
    __shared__ float ldsre[32 * 145];
    __shared__ float ldsim[32 * 145];
    int bid = blockIdx.x, tid = threadIdx.x;
    int c = bid & 63, tbl = (bid >> 6) & 1, l = bid >> 7;
    const float* re = (tbl ? w2re : w1re) + (size_t)((l * 64 + c) * 64) * 144;
    const float* im = (tbl ? w2im : w1im) + (size_t)((l * 64 + c) * 64) * 144;
    int moff = tbl * 144;
    for (int half = 0; half < 2; ++half) {
        __syncthreads();
        for (int i = tid; i < 32 * 144; i += 256) {
            int o = i / 144, m = i - o * 144;
            ldsre[o * 145 + m] = re[(half * 32 + o) * 144 + m];
            ldsim[o * 145 + m] = im[(half * 32 + o) * 144 + m];
        }
        __syncthreads();
        for (int i = tid; i < 32 * 144; i += 256) {
            int mode = i >> 5, o = i & 31;
            Wt[((size_t)(l * 288 + moff + mode) * 64 + c) * 64 + half * 32 + o] =
                make_float2(ldsre[o * 145 + mode], ldsim[o * 145 + mode]);
        }
    }
}

// ---------------- forward DFT over x (fp32, register-tiled) ----------------
__global__ __launch_bounds__(256) void k_dftx(const float* __restrict__ h, const float* __restrict__ Tf_x,
                                              float2* __restrict__ A) {
    __shared__ float hs[64 * 130];
    __shared__ float tfs[24 * 130];
    int blk = blockIdx.x, tid = threadIdx.x;
    const float* src = h + (size_t)blk * 64 * 128;
    for (int i = tid; i < 64 * 128; i += 256) {
        int r = i >> 7, x = i & 127;
        hs[r * 130 + x] = src[i];
    }
    const float2* tfg = (const float2*)Tf_x;
    for (int i = tid; i < 12 * 128; i += 256) {
        int kx = i >> 7, x = i & 127;
        float2 v = tfg[i];
        tfs[(2 * kx) * 130 + x]     = v.x;
        tfs[(2 * kx + 1) * 130 + x] = v.y;
    }
    __syncthreads();
    int rowg = tid & 31, colg = tid >> 5;
    int cb = colg * 3;
    float acc0[3], acc1[3];
#pragma unroll
    for (int k = 0; k < 3; ++k) { acc0[k] = 0.f; acc1[k] = 0.f; }
    const float* h0 = hs + rowg * 130;
    const float* h1 = hs + (rowg + 32) * 130;
#pragma unroll 8
    for (int x = 0; x < 128; x += 2) {
        float2 a = *(const float2*)&h0[x];
        float2 b = *(const float2*)&h1[x];
#pragma unroll
        for (int k = 0; k < 3; ++k) {
            float2 tv = *(const float2*)&tfs[(cb + k) * 130 + x];
            acc0[k] += a.x * tv.x + a.y * tv.y;
            acc1[k] += b.x * tv.x + b.y * tv.y;
        }
    }
    float* dst = (float*)(A + (size_t)blk * 64 * 12);
#pragma unroll
    for (int k = 0; k < 3; ++k) {
        dst[rowg * 24 + cb + k]        = acc0[k];
        dst[(rowg + 32) * 24 + cb + k] = acc1[k];
    }
}

// ---------------- forward DFT over t (fp32) ----------------
__global__ __launch_bounds__(256) void k_dftt(const float2* __restrict__ A, const float* __restrict__ Tf_t,
                                              float2* __restrict__ Hm) {
    __shared__ float2 al[128 * 12];
    __shared__ float2 tt[24 * 129];
    int bc = blockIdx.x, tid = threadIdx.x;
    const float2* src = A + (size_t)bc * 128 * 12;
    for (int i = tid; i < 128 * 12; i += 256) al[i] = src[i];
    const float2* tg = (const float2*)Tf_t;
    for (int i = tid; i < 24 * 128; i += 256) {
        int kt = i >> 7, t = i & 127;
        tt[kt * 129 + t] = tg[i];
    }
    __syncthreads();
    int b = bc >> 6, c = bc & 63;
    for (int oi = tid; oi < 288; oi += 256) {
        int kt = oi / 12, kx = oi - kt * 12;
        float hr = 0.f, hi = 0.f;
        const float2* tp = tt + kt * 129;
#pragma unroll 4
        for (int t = 0; t < 128; ++t) {
            float2 a = al[t * 12 + kx];
            float2 wv = tp[t];
            hr += a.x * wv.x - a.y * wv.y;
            hi += a.x * wv.y + a.y * wv.x;
        }
        Hm[((size_t)oi * 16 + b) * 64 + c] = make_float2(hr, hi);
    }
}

// ---------------- per-mode channel mix (fp32) ----------------
__global__ __launch_bounds__(256) void k_mix(const float2* __restrict__ Hm, const float2* __restrict__ WtL,
                                             float2* __restrict__ Om) {
    __shared__ float2 hl[8 * 64];
    int bid = blockIdx.x, tid = threadIdx.x;
    int mode = bid >> 1, bh = bid & 1;
    const float2* hsrc = Hm + ((size_t)mode * 16 + bh * 8) * 64;
    for (int i = tid; i < 512; i += 256) hl[i] = hsrc[i];
    __syncthreads();
    int o = tid & 63, bg = tid >> 6;
    const float2* wp = WtL + (size_t)mode * 4096 + o;
    const float2* h0 = hl + (bg * 2) * 64;
    const float2* h1 = hl + (bg * 2 + 1) * 64;
    float a0r = 0.f, a0i = 0.f, a1r = 0.f, a1i = 0.f;
#pragma unroll 4
    for (int c = 0; c < 64; ++c) {
        float2 wv = wp[c * 64];
        float2 a0 = h0[c], a1 = h1[c];
        a0r += a0.x * wv.x - a0.y * wv.y;
        a0i += a0.x * wv.y + a0.y * wv.x;
        a1r += a1.x * wv.x - a1.y * wv.y;
        a1i += a1.x * wv.y + a1.y * wv.x;
    }
    int b0 = bh * 8 + bg * 2;
    Om[((size_t)(b0)*64 + o) * 288 + mode]       = make_float2(a0r, a0i);
    Om[((size_t)(b0 + 1) * 64 + o) * 288 + mode] = make_float2(a1r, a1i);
}

__global__ __launch_bounds__(256) void k_mix_raw(const float2* __restrict__ Hm,
                                                 const float* __restrict__ w1re, const float* __restrict__ w1im,
                                                 const float* __restrict__ w2re, const float* __restrict__ w2im,
                                                 float2* __restrict__ Om) {
    __shared__ float2 hl[8 * 64];
    int bid = blockIdx.x, tid = threadIdx.x;
    int mode = bid >> 1, bh = bid & 1;
    const float2* hsrc = Hm + ((size_t)mode * 16 + bh * 8) * 64;
    for (int i = tid; i < 512; i += 256) hl[i] = hsrc[i];
    __syncthreads();
    int kti = mode / 12, kx = mode - kti * 12;
    const float* re; const float* im; int ktw;
    if (kti < 12) { re = w1re; im = w1im; ktw = kti; }
    else          { re = w2re; im = w2im; ktw = kti - 12; }
    int off = ktw * 12 + kx;
    int o = tid & 63, bg = tid >> 6;
    const float2* h0 = hl + (bg * 2) * 64;
    const float2* h1 = hl + (bg * 2 + 1) * 64;
    float a0r = 0.f, a0i = 0.f, a1r = 0.f, a1i = 0.f;
    for (int c = 0; c < 64; ++c) {
        size_t widx = (size_t)(c * 64 + o) * 144 + off;
        float wr = re[widx], wi = im[widx];
        float2 a0 = h0[c], a1 = h1[c];
        a0r += a0.x * wr - a0.y * wi;
        a0i += a0.x * wi + a0.y * wr;
        a1r += a1.x * wr - a1.y * wi;
        a1i += a1.x * wi + a1.y * wr;
    }
    int b0 = bh * 8 + bg * 2;
    Om[((size_t)(b0)*64 + o) * 288 + mode]       = make_float2(a0r, a0i);
    Om[((size_t)(b0 + 1) * 64 + o) * 288 + mode] = make_float2(a1r, a1i);
}

// ---------------- inverse DFT over t (fp32) ----------------
__global__ __launch_bounds__(256) void k_idftt(const float2* __restrict__ Om, const float* __restrict__ Ti_t,
                                               float2* __restrict__ B) {
    __shared__ float2 ol[288];
    __shared__ float2 tt[24 * 129];
    int bo = blockIdx.x, tid = threadIdx.x;
    const float2* src = Om + (size_t)bo * 288;
    for (int i = tid; i < 288; i += 256) ol[i] = src[i];
    const float2* tg = (const float2*)Ti_t;
    for (int i = tid; i < 24 * 128; i += 256) {
        int kt = i >> 7, t = i & 127;
        tt[kt * 129 + t] = tg[i];
    }
    __syncthreads();
    float2* dst = B + (size_t)bo * 128 * 12;
#pragma unroll
    for (int k = 0; k < 6; ++k) {
        int oi = tid + k * 256;
        int t = oi / 12, kx = oi - t * 12;
        float br = 0.f, bi = 0.f;
#pragma unroll
        for (int kt = 0; kt < 24; ++kt) {
            float2 a = ol[kt * 12 + kx];
            float2 wv = tt[kt * 129 + t];
            br += a.x * wv.x - a.y * wv.y;
            bi += a.x * wv.y + a.y * wv.x;
        }
        dst[oi] = make_float2(br, bi);
    }
}

// ---------------- conv + idft-x via split-bf16 MFMA ----------------
// block=(b,t,xh): out[o=64][x=64] = sum_{k=0..87} A[o][k] B[x][k]
//   k 0..63: W(o,c) * h(c,x);  k 64..87: S(o,kk) * T(kk,x)  (spectral, re/im planes)
// split-bf16: acc = Ah*Bh + Ah*Bl + Al*Bh.
template <int DOGELU>
__global__ __launch_bounds__(256) void k_conv_mfma(float* __restrict__ h, const float2* __restrict__ Bv,
                                                   const float* __restrict__ wconv, const float* __restrict__ bconv,
                                                   const float* __restrict__ Ti_x) {
    __shared__ float hs[64][68];               // stage1 h[c][x]
    __shared__ unsigned short Ah[64][104], Al[64][104];   // [o][k]
    __shared__ unsigned short Bh[64][104], Bl[64][104];   // [x][k]
    int bid = blockIdx.x, tid = threadIdx.x;
    int xh = bid & 1, t = (bid >> 1) & 127, b = bid >> 8;
    float* hb = h + ((size_t)(b * 64) * 128 + t) * 128 + xh * 64;

    // --- phase 1 staging ---
    // W -> A cols 0..63
    for (int i4 = tid; i4 < 1024; i4 += 256) {
        int o = i4 >> 4, c4 = (i4 & 15) << 2;
        float4 wv = *reinterpret_cast<const float4*>(&wconv[o * 64 + c4]);
        unsigned short hh[4], ll[4];
        split2(wv.x, hh[0], ll[0]); split2(wv.y, hh[1], ll[1]);
        split2(wv.z, hh[2], ll[2]); split2(wv.w, hh[3], ll[3]);
        *reinterpret_cast<uint2*>(&Ah[o][c4]) =
            make_uint2((unsigned)hh[0] | ((unsigned)hh[1] << 16), (unsigned)hh[2] | ((unsigned)hh[3] << 16));
        *reinterpret_cast<uint2*>(&Al[o][c4]) =
            make_uint2((unsigned)ll[0] | ((unsigned)ll[1] << 16), (unsigned)ll[2] | ((unsigned)ll[3] << 16));
    }
    // spectral S -> A cols 64..87
    const float2* bsrc = Bv + ((size_t)(b * 64) * 128 + t) * 12;
    for (int i = tid; i < 768; i += 256) {
        int o = i / 12, kx = i - o * 12;
        float2 bv = bsrc[(size_t)o * 1536 + kx];
        unsigned short hr, lr, hi, li;
        split2(bv.x, hr, lr); split2(bv.y, hi, li);
        Ah[o][64 + 2 * kx] = hr; Al[o][64 + 2 * kx] = lr;
        Ah[o][65 + 2 * kx] = hi; Al[o][65 + 2 * kx] = li;
    }
    // Ti_x table -> B cols 64..87 (re: w*cos, im: -w*sin)
    const float2* tg = (const float2*)Ti_x;
    for (int i = tid; i < 768; i += 256) {
        int x = i & 63, kx = i >> 6;
        float2 ti = tg[kx * 128 + xh * 64 + x];
        unsigned short hr, lr, hi, li;
        split2(ti.x, hr, lr); split2(-ti.y, hi, li);
        Bh[x][64 + 2 * kx] = hr; Bl[x][64 + 2 * kx] = lr;
        Bh[x][65 + 2 * kx] = hi; Bl[x][65 + 2 * kx] = li;
    }
    // zero pad k = 88..95 (read by ktile 2)
    {
        int row = tid & 63, which = tid >> 6;
        uint4 z = make_uint4(0, 0, 0, 0);
        if (which == 0) *reinterpret_cast<uint4*>(&Ah[row][88]) = z;
        else if (which == 1) *reinterpret_cast<uint4*>(&Al[row][88]) = z;
        else if (which == 2) *reinterpret_cast<uint4*>(&Bh[row][88]) = z;
        else *reinterpret_cast<uint4*>(&Bl[row][88]) = z;
    }
    // h -> hs fp32
    for (int i4 = tid; i4 < 1024; i4 += 256) {
        int c = i4 >> 4, x4 = (i4 & 15) << 2;
        float4 hv = *reinterpret_cast<const float4*>(&hb[(size_t)c * 16384 + x4]);
        *reinterpret_cast<float4*>(&hs[c][x4]) = hv;
    }
    __syncthreads();

    // --- phase 2: transpose-convert h into B cols 0..63 ---
    {
        int x = tid & 63, cb = tid >> 6;
#pragma unroll
        for (int rep = 0; rep < 2; ++rep) {
            int c0 = cb * 8 + rep * 32;
            unsigned short hh[8], ll[8];
#pragma unroll
            for (int j = 0; j < 8; ++j) split2(hs[c0 + j][x], hh[j], ll[j]);
            *reinterpret_cast<uint4*>(&Bh[x][c0]) = make_uint4(
                (unsigned)hh[0] | ((unsigned)hh[1] << 16), (unsigned)hh[2] | ((unsigned)hh[3] << 16),
                (unsigned)hh[4] | ((unsigned)hh[5] << 16), (unsigned)hh[6] | ((unsigned)hh[7] << 16));
            *reinterpret_cast<uint4*>(&Bl[x][c0]) = make_uint4(
                (unsigned)ll[0] | ((unsigned)ll[1] << 16), (unsigned)ll[2] | ((unsigned)ll[3] << 16),
                (unsigned)ll[4] | ((unsigned)ll[5] << 16), (unsigned)ll[6] | ((unsigned)ll[7] << 16));
        }
    }
    __syncthreads();

    // --- MFMA ---
    int w = tid >> 6, lane = tid & 63;
    int ln = lane & 15, lg = lane >> 4;
    int mo = w;                       // o-stripe = w*16
    f32x4 acc[4];
#pragma unroll
    for (int nx = 0; nx < 4; ++nx) acc[nx] = (f32x4){0.f, 0.f, 0.f, 0.f};
#pragma unroll
    for (int kt = 0; kt < 3; ++kt) {
        short8 af_h = *reinterpret_cast<const short8*>(&Ah[mo * 16 + ln][kt * 32 + lg * 8]);
        short8 af_l = *reinterpret_cast<const short8*>(&Al[mo * 16 + ln][kt * 32 + lg * 8]);
#pragma unroll
        for (int nx = 0; nx < 4; ++nx) {
            short8 bf_h = *reinterpret_cast<const short8*>(&Bh[nx * 16 + ln][kt * 32 + lg * 8]);
            short8 bf_l = *reinterpret_cast<const short8*>(&Bl[nx * 16 + ln][kt * 32 + lg * 8]);
            acc[nx] = __builtin_amdgcn_mfma_f32_16x16x32_bf16(af_h, bf_h, acc[nx], 0, 0, 0);
            acc[nx] = __builtin_amdgcn_mfma_f32_16x16x32_bf16(af_h, bf_l, acc[nx], 0, 0, 0);
            acc[nx] = __builtin_amdgcn_mfma_f32_16x16x32_bf16(af_l, bf_h, acc[nx], 0, 0, 0);
        }
    }
    // --- epilogue ---
#pragma unroll
    for (int r = 0; r < 4; ++r) {
        int o = mo * 16 + lg * 4 + r;
        float bc = bconv[o];
#pragma unroll
        for (int nx = 0; nx < 4; ++nx) {
            float v = acc[nx][r] + bc;
            if (DOGELU) v = 0.5f * v * (1.0f + erff(v * 0.70710678118654752f));
            hb[(size_t)o * 16384 + nx * 16 + ln] = v;
        }
    }
}

// ---------------- head via split-bf16 MFMA: fc1 + gelu + fc2 ----------------
// block=(b,t,xh): acc[d=128][x=64] = sum_c W1[d][c] h[c][x]; gelu; out[x]=sum_d g*w2[d]+b2
__global__ __launch_bounds__(256) void k_head_mfma(const float* __restrict__ h, const float* __restrict__ w1,
                                                   const float* __restrict__ b1, const float* __restrict__ w2,
                                                   const float* __restrict__ b2, float* __restrict__ out) {
    __shared__ float hs[64][68];
    __shared__ unsigned short Ah[128][72], Al[128][72];   // [d][c]
    __shared__ unsigned short Bh[64][72], Bl[64][72];     // [x][c]
    __shared__ float red[16][66];
    int bid = blockIdx.x, tid = threadIdx.x;
    int xh = bid & 1, t = (bid >> 1) & 127, b = bid >> 8;
    const float* hb = h + ((size_t)(b * 64) * 128 + t) * 128 + xh * 64;

    // stage W1
    for (int i4 = tid; i4 < 2048; i4 += 256) {
        int d = i4 >> 4, c4 = (i4 & 15) << 2;
        float4 wv = *reinterpret_cast<const float4*>(&w1[d * 64 + c4]);
        unsigned short hh[4], ll[4];
        split2(wv.x, hh[0], ll[0]); split2(wv.y, hh[1], ll[1]);
        split2(wv.z, hh[2], ll[2]); split2(wv.w, hh[3], ll[3]);
        *reinterpret_cast<uint2*>(&Ah[d][c4]) =
            make_uint2((unsigned)hh[0] | ((unsigned)hh[1] << 16), (unsigned)hh[2] | ((unsigned)hh[3] << 16));
        *reinterpret_cast<uint2*>(&Al[d][c4]) =
            make_uint2((unsigned)ll[0] | ((unsigned)ll[1] << 16), (unsigned)ll[2] | ((unsigned)ll[3] << 16));
    }
    // stage h
    for (int i4 = tid; i4 < 1024; i4 += 256) {
        int c = i4 >> 4, x4 = (i4 & 15) << 2;
        float4 hv = *reinterpret_cast<const float4*>(&hb[(size_t)c * 16384 + x4]);
        *reinterpret_cast<float4*>(&hs[c][x4]) = hv;
    }
    __syncthreads();
    // transpose-convert
    {
        int x = tid & 63, cb = tid >> 6;
#pragma unroll
        for (int rep = 0; rep < 2; ++rep) {
            int c0 = cb * 8 + rep * 32;
            unsigned short hh[8], ll[8];
#pragma unroll
            for (int j = 0; j < 8; ++j) split2(hs[c0 + j][x], hh[j], ll[j]);
            *reinterpret_cast<uint4*>(&Bh[x][c0]) = make_uint4(
                (unsigned)hh[0] | ((unsigned)hh[1] << 16), (unsigned)hh[2] | ((unsigned)hh[3] << 16),
                (unsigned)hh[4] | ((unsigned)hh[5] << 16), (unsigned)hh[6] | ((unsigned)hh[7] << 16));
            *reinterpret_cast<uint4*>(&Bl[x][c0]) = make_uint4(
                (unsigned)ll[0] | ((unsigned)ll[1] << 16), (unsigned)ll[2] | ((unsigned)ll[3] << 16),
                (unsigned)ll[4] | ((unsigned)ll[5] << 16), (unsigned)ll[6] | ((unsigned)ll[7] << 16));
        }
    }
    __syncthreads();

    int w = tid >> 6, lane = tid & 63;
    int ln = lane & 15, lg = lane >> 4;
    f32x4 acc[2][4];
#pragma unroll
    for (int s = 0; s < 2; ++s)
#pragma unroll
        for (int nx = 0; nx < 4; ++nx) acc[s][nx] = (f32x4){0.f, 0.f, 0.f, 0.f};
#pragma unroll
    for (int kt = 0; kt < 2; ++kt) {
        short8 bf_h[4], bf_l[4];
#pragma unroll
        for (int nx = 0; nx < 4; ++nx) {
            bf_h[nx] = *reinterpret_cast<const short8*>(&Bh[nx * 16 + ln][kt * 32 + lg * 8]);
            bf_l[nx] = *reinterpret_cast<const short8*>(&Bl[nx * 16 + ln][kt * 32 + lg * 8]);
        }
#pragma unroll
        for (int s = 0; s < 2; ++s) {
            int d0 = (w * 2 + s) * 16 + ln;
            short8 af_h = *reinterpret_cast<const short8*>(&Ah[d0][kt * 32 + lg * 8]);
            short8 af_l = *reinterpret_cast<const short8*>(&Al[d0][kt * 32 + lg * 8]);
#pragma unroll
            for (int nx = 0; nx < 4; ++nx) {
                acc[s][nx] = __builtin_amdgcn_mfma_f32_16x16x32_bf16(af_h, bf_h[nx], acc[s][nx], 0, 0, 0);
                acc[s][nx] = __builtin_amdgcn_mfma_f32_16x16x32_bf16(af_h, bf_l[nx], acc[s][nx], 0, 0, 0);
                acc[s][nx] = __builtin_amdgcn_mfma_f32_16x16x32_bf16(af_l, bf_h[nx], acc[s][nx], 0, 0, 0);
            }
        }
    }
    // gelu + fc2 partial
    float p[4];
#pragma unroll
    for (int nx = 0; nx < 4; ++nx) p[nx] = 0.f;
#pragma unroll
    for (int s = 0; s < 2; ++s)
#pragma unroll
        for (int r = 0; r < 4; ++r) {
            int d = (w * 2 + s) * 16 + lg * 4 + r;
            float bb = b1[d], wk = w2[d];
#pragma unroll
            for (int nx = 0; nx < 4; ++nx) {
                float v = acc[s][nx][r] + bb;
                float g = 0.5f * v * (1.0f + erff(v * 0.70710678118654752f));
                p[nx] += g * wk;
            }
        }
#pragma unroll
    for (int nx = 0; nx < 4; ++nx) red[w * 4 + lg][nx * 16 + ln] = p[nx];
    __syncthreads();
    if (tid < 64) {
        float s = 0.f;
#pragma unroll
        for (int g = 0; g < 16; ++g) s += red[g][tid];
        out[((size_t)b * 128 + t) * 128 + xh * 64 + tid] = s + b2[0];
    }
}

extern "C" void kernel_launch(void* const* d_in, const int* in_sizes, int n_in,
                              void* d_out, int out_size, void* d_ws, size_t ws_size,
                              hipStream_t stream) {
    const float* ts    = (const float*)d_in[0];
    const float* xs    = (const float*)d_in[1];
    const float* u0    = (const float*)d_in[2];
    const float* fc0_w = (const float*)d_in[3];
    const float* fc0_b = (const float*)d_in[4];
    const float* w1re  = (const float*)d_in[5];
    const float* w1im  = (const float*)d_in[6];
    const float* w2re  = (const float*)d_in[7];
    const float* w2im  = (const float*)d_in[8];
    const float* wconv = (const float*)d_in[9];
    const float* bconv = (const float*)d_in[10];
    const float* fc1w  = (const float*)d_in[11];
    const float* fc1b  = (const float*)d_in[12];
    const float* fc2w  = (const float*)d_in[13];
    const float* fc2b  = (const float*)d_in[14];
    float* out = (float*)d_out;

    char* ws = (char*)d_ws;
    size_t off = 0;
    auto alloc = [&](size_t bytes) -> char* {
        char* p = ws + off;
        off = (off + bytes + 255) & ~(size_t)255;
        return p;
    };
    float*  h    = (float*)alloc(67108864);          // [16][64][128][128]
    float2* A    = (float2*)alloc(12582912);         // [16*64*128][12]
    float2* Hm   = (float2*)alloc(2359296);          // [288][16][64]
    float2* Om   = (float2*)alloc(2359296);          // [16][64][288]
    float2* Bv   = (float2*)alloc(12582912);         // [16*64][128][12]
    float*  U    = (float*)alloc(4096);
    float*  Tf_x = (float*)alloc(12288);
    float*  Tf_t = (float*)alloc(24576);
    float*  Ti_t = (float*)alloc(24576);
    float*  Ti_x = (float*)alloc(12288);
    size_t base_need = off;
    if (ws_size < base_need) return;
    float2* Wt = (float2*)alloc(37748736);           // [4][288][64][64]
    bool use_wt = (ws_size >= off);

    k_tables<<<1, 256, 0, stream>>>(Tf_x, Tf_t, Ti_t, Ti_x);
    k_u<<<16, 64, 0, stream>>>(u0, fc0_w, fc0_b, U);
    k_fc0<<<16384, 256, 0, stream>>>(xs, ts, fc0_w, U, h);
    if (use_wt)
        k_wt<<<512, 256, 0, stream>>>(w1re, w1im, w2re, w2im, Wt);

    for (int l = 0; l < 4; ++l) {
        k_dftx<<<2048, 256, 0, stream>>>(h, Tf_x, A);
        k_dftt<<<1024, 256, 0, stream>>>(A, Tf_t, Hm);
        if (use_wt)
            k_mix<<<576, 256, 0, stream>>>(Hm, Wt + (size_t)l * 288 * 4096, Om);
        else
            k_mix_raw<<<576, 256, 0, stream>>>(Hm, w1re + (size_t)l * 589824, w1im + (size_t)l * 589824,
                                               w2re + (size_t)l * 589824, w2im + (size_t)l * 589824, Om);
        k_idftt<<<1024, 256, 0, stream>>>(Om, Ti_t, Bv);
        if (l < 3)
            k_conv_mfma<1><<<4096, 256, 0, stream>>>(h, Bv, wconv + l * 4096, bconv + l * 64, Ti_x);
        else
            k_conv_mfma<0><<<4096, 256, 0, stream>>>(h, Bv, wconv + l * 4096, bconv + l * 64, Ti_x);
    }
    k_head_mfma<<<4096, 256, 0, stream>>>(h, fc1w, fc1b, fc2w, fc2b, out);
}